// Round 6
// baseline (1561.917 us; speedup 1.0000x reference)
//
#include <hip/hip_runtime.h>
#include <hip/hip_bf16.h>

// ---- problem constants (match reference) ----
#define NYI 200
#define NXI 200
#define PMLW 20
#define FDP 2
#define PADW (PMLW + FDP)          // 22
#define NYP (NYI + 2 * PADW)       // 244
#define NXP (NXI + 2 * PADW)       // 244
#define NP  (NYP * NXP)            // 59536
#define NSH 2
#define NRECV 100
#define NTT 120
#define TOTC (NSH * NP)            // 119072

#define DTC   0.0005f
#define RH    0.25f
#define RH2   0.0625f
#define C1A   (1.0f / 12.0f)
#define C1B   (2.0f / 3.0f)
#define C2A   (1.0f / 12.0f)
#define C2B   (4.0f / 3.0f)

// ---- workspace layout (float offsets) ----
#define OFF_MAXV 0
#define OFF_AY   64
#define OFF_BY   (OFF_AY + NYP)
#define OFF_AX   (OFF_BY + NYP)
#define OFF_BX   (OFF_AX + NXP)
#define OFF_V2   (OFF_BX + NXP)
#define OFF_SPV  (OFF_V2 + NP)
#define OFF_F    (OFF_SPV + NP)      // 24 * TOTC floats of fields

// global array slots (per field: 12; field offset = 12)
//  0..3  : w rotation (4 buffers)
//  4,5   : psiy A/B     6,7: psix A/B     8,9: zety A/B    10,11: zetx A/B

#define LSTRIDE 33   // 32 cols + 1 pad (bank-conflict break)

__global__ void reduce_max_kernel(const float* __restrict__ v, float* __restrict__ out) {
    __shared__ float sm[256];
    float m = 0.0f;
    for (int i = threadIdx.x; i < NYI * NXI; i += 256)
        m = fmaxf(m, v[i]);
    sm[threadIdx.x] = m;
    __syncthreads();
    for (int s = 128; s > 0; s >>= 1) {
        if (threadIdx.x < s) sm[threadIdx.x] = fmaxf(sm[threadIdx.x], sm[threadIdx.x + s]);
        __syncthreads();
    }
    if (threadIdx.x == 0) out[0] = sm[0];
}

__global__ void setup_kernel(const float* __restrict__ v,
                             const float* __restrict__ scat,
                             const float* __restrict__ maxv,
                             float* __restrict__ ay, float* __restrict__ by,
                             float* __restrict__ ax, float* __restrict__ bx,
                             float* __restrict__ v2dt2, float* __restrict__ spv) {
    int gtid = blockIdx.x * blockDim.x + threadIdx.x;
    int nth  = gridDim.x * blockDim.x;

    for (int idx = gtid; idx < NP; idx += nth) {
        int y = idx / NXP;
        int x = idx - y * NXP;
        int yi = min(max(y - PADW, 0), NYI - 1);
        int xi = min(max(x - PADW, 0), NXI - 1);
        float vp = v[yi * NXI + xi];
        v2dt2[idx] = vp * vp * DTC * DTC;
        float sp = 0.0f;
        int ys = y - PADW, xs = x - PADW;
        if (ys >= 0 && ys < NYI && xs >= 0 && xs < NXI)
            sp = scat[ys * NXI + xs];
        spv[idx] = 2.0f * vp * DTC * DTC * sp;
    }

    if (gtid < NYP + NXP) {
        float mv = maxv[0];
        int isY = gtid < NYP;
        int j   = isY ? gtid : gtid - NYP;
        int n   = isY ? NYP : NXP;
        float h = 4.0f;
        float xf = (float)j;
        float lo = (float)(FDP + PMLW);
        float hi = (float)(n - 1 - FDP - PMLW);
        float d1 = fminf(fmaxf((lo - xf) / (float)PMLW, 0.0f), 1.0f);
        float d2 = fminf(fmaxf((xf - hi) / (float)PMLW, 0.0f), 1.0f);
        float d  = fmaxf(d1, d2);
        float sigma = 3.0f * mv * 6.9077552790f / (2.0f * (float)PMLW * h) * d * d;
        float alpha = 6.2831853072f * 25.0f * (1.0f - d);
        float a  = expf(-(sigma + alpha) * DTC);
        float bb = sigma / (sigma + alpha + 1e-9f) * (a - 1.0f);
        if (isY) { ay[j] = a; by[j] = bb; }
        else     { ax[j] = a; bx[j] = bb; }
    }
}

// Two fused time steps (t and t+1) on a 32x32 LDS tile (16x16 interior).
// Valid regions shrink by 2 per phase: psi(t+1):[2,29], w(t+1)/zeta(t+1):[4,27],
// psi(t+2):[6,25], w(t+2)/zeta(t+2):[8,23]=interior.
// Global buffers: w 4-rotation, psi/zeta A/B ping-pong -> outputs disjoint
// from inputs, so inter-tile halo reads are race-free (launch-ordered steps).
__global__ void __launch_bounds__(256)
superstep_kernel(int t, int hw2, int nt, int p,
                 float* __restrict__ F,
                 const float* __restrict__ ay, const float* __restrict__ by,
                 const float* __restrict__ ax, const float* __restrict__ bx,
                 const float* __restrict__ v2dt2, const float* __restrict__ spv,
                 const float* __restrict__ amps, const int* __restrict__ sloc,
                 const int* __restrict__ rloc, float* __restrict__ out)
{
    __shared__ float L[12][32 * LSTRIDE];

    const int tid = threadIdx.x;
    const int ntt2 = nt * nt;
    const int b  = blockIdx.x / ntt2;
    const int rr = blockIdx.x - b * ntt2;
    const int ti = rr / nt, tj = rr - ti * nt;

    const int sy = sloc[2 * b + 0] + PADW;
    const int sx = sloc[2 * b + 1] + PADW;
    const int oy = sy - hw2 + ti * 16 - 8;   // stage origin
    const int ox = sx - hw2 + tj * 16 - 8;
    const int boff = b * NP;

    // parity-derived global slots
    const int Wc  = p ? 2 : 0;   // w(t)
    const int Wp_ = p ? 3 : 1;   // w(t-1)
    const int Wn2 = p ? 0 : 2;   // w(t+2) out
    const int Wn1 = p ? 1 : 3;   // w(t+1) out
    const int PYa = 4 + p,  PYb = 5 - p;
    const int PXa = 6 + p,  PXb = 7 - p;
    const int ZYa = 8 + p,  ZYb = 9 - p;
    const int ZXa = 10 + p, ZXb = 11 - p;
    const int gslot[6] = {Wc, Wp_, PYa, PXa, ZYa, ZXa};

    // ---- stage 12 arrays (6 per field) ----
    for (int i = tid; i < 12 * 1024; i += 256) {
        int arr = i >> 10, e = i & 1023;
        int ly = e >> 5, lx = e & 31;
        int f = arr / 6, sl = arr - f * 6;
        int gy = oy + ly, gx = ox + lx;
        float val = 0.0f;
        if ((unsigned)gy < (unsigned)NYP && (unsigned)gx < (unsigned)NXP)
            val = F[(f * 12 + gslot[sl]) * (long)TOTC + boff + gy * NXP + gx];
        L[f * 6 + sl][ly * LSTRIDE + lx] = val;
    }
    __syncthreads();

    const float amp0 = amps[b * NTT + t];
    const float amp1 = amps[b * NTT + t + 1];
    const int lsy = sy - oy, lsx = sx - ox;

#pragma unroll
    for (int k = 0; k < 2; ++k) {
        const int cw = k;        // LDS slot holding current w
        const int pw = 1 - k;    // LDS slot holding prev w (also dst for new w)

        // ---- phase P: psi update (in-place, own-cell) ----
        {
            int lo = 2 + 4 * k, n = 32 - 2 * lo;
            for (int i = tid; i < n * n; i += 256) {
                int ly = lo + i / n, lx = lo + (i - (i / n) * n);
                int gy = oy + ly, gx = ox + lx;
                bool m = ((unsigned)gy < (unsigned)NYP) && ((unsigned)gx < (unsigned)NXP);
                int cy = min(max(gy, 0), NYP - 1), cx = min(max(gx, 0), NXP - 1);
                float ayv = ay[cy], byv = by[cy], axv = ax[cx], bxv = bx[cx];
                int c = ly * LSTRIDE + lx;
#pragma unroll
                for (int f = 0; f < 2; ++f) {
                    const float* Lw = L[f * 6 + cw];
                    float d1y = RH * (C1A * (Lw[c - 2 * LSTRIDE] - Lw[c + 2 * LSTRIDE]) +
                                      C1B * (Lw[c + LSTRIDE] - Lw[c - LSTRIDE]));
                    float d1x = RH * (C1A * (Lw[c - 2] - Lw[c + 2]) +
                                      C1B * (Lw[c + 1] - Lw[c - 1]));
                    float* Lpy = L[f * 6 + 2];
                    float* Lpx = L[f * 6 + 3];
                    float pyn = m ? (ayv * Lpy[c] + byv * d1y) : 0.0f;
                    float pxn = m ? (axv * Lpx[c] + bxv * d1x) : 0.0f;
                    Lpy[c] = pyn;
                    Lpx[c] = pxn;
                }
            }
        }
        __syncthreads();

        // ---- phase W: zeta + wavefield update (writes into pw slot) ----
        {
            int lo = 4 + 4 * k, n = 32 - 2 * lo;
            for (int i = tid; i < n * n; i += 256) {
                int ly = lo + i / n, lx = lo + (i - (i / n) * n);
                int gy = oy + ly, gx = ox + lx;
                bool m = ((unsigned)gy < (unsigned)NYP) && ((unsigned)gx < (unsigned)NXP);
                int cy = min(max(gy, 0), NYP - 1), cx = min(max(gx, 0), NXP - 1);
                float ayv = ay[cy], byv = by[cy], axv = ax[cx], bxv = bx[cx];
                int cell = cy * NXP + cx;
                float v2 = v2dt2[cell], sv = spv[cell];
                int c = ly * LSTRIDE + lx;
                float lapbg = 0.0f;
#pragma unroll
                for (int f = 0; f < 2; ++f) {
                    float* Lw  = L[f * 6 + cw];
                    float* Lwp = L[f * 6 + pw];
                    float* Lpy = L[f * 6 + 2];
                    float* Lpx = L[f * 6 + 3];
                    float* Lzy = L[f * 6 + 4];
                    float* Lzx = L[f * 6 + 5];
                    float w0 = Lw[c];
                    float d2y = RH2 * (C2B * (Lw[c - LSTRIDE] + Lw[c + LSTRIDE]) -
                                       C2A * (Lw[c - 2 * LSTRIDE] + Lw[c + 2 * LSTRIDE]) -
                                       2.5f * w0);
                    float d2x = RH2 * (C2B * (Lw[c - 1] + Lw[c + 1]) -
                                       C2A * (Lw[c - 2] + Lw[c + 2]) -
                                       2.5f * w0);
                    float d1yp = RH * (C1A * (Lpy[c - 2 * LSTRIDE] - Lpy[c + 2 * LSTRIDE]) +
                                       C1B * (Lpy[c + LSTRIDE] - Lpy[c - LSTRIDE]));
                    float d1xp = RH * (C1A * (Lpx[c - 2] - Lpx[c + 2]) +
                                       C1B * (Lpx[c + 1] - Lpx[c - 1]));
                    float ty = d2y + d1yp;
                    float tx = d2x + d1xp;
                    float zy = ayv * Lzy[c] + byv * ty;
                    float zx = axv * Lzx[c] + bxv * tx;
                    float lap = ty + zy + tx + zx;
                    float wn;
                    if (f == 0) {
                        lapbg = lap;
                        wn = v2 * lap + 2.0f * w0 - Lwp[c];
                        if (ly == lsy && lx == lsx) wn += v2 * (k ? amp1 : amp0);
                    } else {
                        wn = v2 * lap + 2.0f * w0 - Lwp[c] + sv * lapbg;
                    }
                    if (!m) { wn = 0.0f; zy = 0.0f; zx = 0.0f; }
                    Lzy[c] = zy;
                    Lzx[c] = zx;
                    Lwp[c] = wn;   // dst == pw (prev slot), own-cell in-place
                }
            }
        }
        __syncthreads();
    }

    // ---- write back 16x16 interior ----
    {
        int ly = 8 + (tid >> 4), lx = 8 + (tid & 15);
        int gy = oy + ly, gx = ox + lx;
        if ((unsigned)gy < (unsigned)NYP && (unsigned)gx < (unsigned)NXP) {
            int g = boff + gy * NXP + gx;
            int c = ly * LSTRIDE + lx;
#pragma unroll
            for (int f = 0; f < 2; ++f) {
                F[(f * 12 + Wn2) * (long)TOTC + g] = L[f * 6 + 0][c];  // w(t+2)
                F[(f * 12 + Wn1) * (long)TOTC + g] = L[f * 6 + 1][c];  // w(t+1)
                F[(f * 12 + PYb) * (long)TOTC + g] = L[f * 6 + 2][c];
                F[(f * 12 + PXb) * (long)TOTC + g] = L[f * 6 + 3][c];
                F[(f * 12 + ZYb) * (long)TOTC + g] = L[f * 6 + 4][c];
                F[(f * 12 + ZXb) * (long)TOTC + g] = L[f * 6 + 5][c];
            }
        }
    }

    // ---- receivers: out[:,:,t] = w_sc(t+1), out[:,:,t+1] = w_sc(t+2) ----
    if (tid < NRECV) {
        int gy = rloc[(b * NRECV + tid) * 2 + 0] + PADW;
        int gx = rloc[(b * NRECV + tid) * 2 + 1] + PADW;
        int ly = gy - oy, lx = gx - ox;
        if (ly >= 8 && ly < 24 && lx >= 8 && lx < 24) {
            int c = ly * LSTRIDE + lx;
            out[(b * NRECV + tid) * NTT + t]     = L[6 + 1][c];  // sc field slot1 = w(t+1)
            out[(b * NRECV + tid) * NTT + t + 1] = L[6 + 0][c];  // sc field slot0 = w(t+2)
        }
    }
    // receivers outside the tiled union: true value negligible -> write 0
    if (ti == 0 && tj == 0 && tid < NRECV) {
        int gy = rloc[(b * NRECV + tid) * 2 + 0] + PADW;
        int gx = rloc[(b * NRECV + tid) * 2 + 1] + PADW;
        int u0y = sy - hw2, u0x = sx - hw2, span = 16 * nt;
        if (gy < u0y || gy >= u0y + span || gx < u0x || gx >= u0x + span) {
            out[(b * NRECV + tid) * NTT + t]     = 0.0f;
            out[(b * NRECV + tid) * NTT + t + 1] = 0.0f;
        }
    }
}

extern "C" void kernel_launch(void* const* d_in, const int* in_sizes, int n_in,
                              void* d_out, int out_size, void* d_ws, size_t ws_size,
                              hipStream_t stream) {
    const float* v    = (const float*)d_in[0];
    const float* scat = (const float*)d_in[1];
    const float* amps = (const float*)d_in[2];
    const int* sloc = (const int*)d_in[3];
    const int* rloc = (const int*)d_in[4];
    float* ws = (float*)d_ws;
    float* out = (float*)d_out;

    float* ay  = ws + OFF_AY;
    float* by  = ws + OFF_BY;
    float* ax  = ws + OFF_AX;
    float* bx  = ws + OFF_BX;
    float* v2  = ws + OFF_V2;
    float* spv = ws + OFF_SPV;
    float* F   = ws + OFF_F;

    // zero the 24 field arrays (ws poisoned 0xAA before every timed call)
    hipMemsetAsync(F, 0, sizeof(float) * 24 * (size_t)TOTC, stream);

    reduce_max_kernel<<<1, 256, 0, stream>>>(v, ws + OFF_MAXV);
    setup_kernel<<<(NP + 255) / 256, 256, 0, stream>>>(
        v, scat, ws + OFF_MAXV, ay, by, ax, bx, v2, spv);

    for (int s = 0; s < NTT / 2; ++s) {
        int t = 2 * s;
        int hw2 = 20 + (int)(0.35f * (float)(t + 2));
        int nt = (2 * hw2 + 1 + 15) / 16;
        int blocks = 2 * nt * nt;
        superstep_kernel<<<blocks, 256, 0, stream>>>(
            t, hw2, nt, s & 1,
            F, ay, by, ax, bx, v2, spv, amps, sloc, rloc, out);
    }
}